// Round 4
// baseline (3630.915 us; speedup 1.0000x reference)
//
#include <hip/hip_runtime.h>

#define NB 32
#define FC 1024
#define DD 512
#define HH 1024
#define BN_EPS 1e-5f

typedef unsigned short u16;
typedef unsigned int u32;

__device__ __forceinline__ float b2f(u16 u) {
    union { u32 i; float f; } v;
    v.i = ((u32)u) << 16;
    return v.f;
}
__device__ __forceinline__ u16 f2b(float f) {
    union { float f; u32 i; } v;
    v.f = f;
    const u32 b = v.i;
    return (u16)((b + 0x7FFFu + ((b >> 16) & 1u)) >> 16);
}

// ---------------------------------------------------------------------------
// Dtype detection: flag=1 if buffer is bf16 pairs, 0 if fp32.
// For bf16 N(0,1) data the low u16 of each u32 word is itself a bf16 value
// with exponent in a sane range (~100% hit). For fp32 data the low u16 is
// raw mantissa bits (~uniform) -> ~12% hit. Threshold at 50%.
// ---------------------------------------------------------------------------
__global__ __launch_bounds__(256) void detect_dtype(
    const u32* __restrict__ x, int* __restrict__ flag)
{
    __shared__ int cnt[256];
    int c = 0;
    for (int i = threadIdx.x; i < 4096; i += 256) {
        const u32 lo = x[i] & 0xFFFFu;
        const u32 e = (lo >> 7) & 0xFFu;
        if (e >= 0x68u && e <= 0x85u) c++;
    }
    cnt[threadIdx.x] = c;
    __syncthreads();
    for (int s = 128; s > 0; s >>= 1) {
        if (threadIdx.x < (unsigned)s) cnt[threadIdx.x] += cnt[threadIdx.x + s];
        __syncthreads();
    }
    if (threadIdx.x == 0) flag[0] = (cnt[0] > 2048) ? 1 : 0;
}

// Convert a tensor (bf16 or fp32 per flag) to bf16. n4 = count/4.
__global__ __launch_bounds__(256) void convert_to_bf16(
    const void* __restrict__ src, u16* __restrict__ dst, long n4,
    const int* __restrict__ flag)
{
    const bool isbf = (*flag != 0);
    long i4 = (long)blockIdx.x * blockDim.x + threadIdx.x;
    const long stride = (long)gridDim.x * blockDim.x;
    for (; i4 < n4; i4 += stride) {
        const long i = i4 << 2;
        if (isbf) {
            *(ushort4*)(dst + i) = *(const ushort4*)((const u16*)src + i);
        } else {
            const float4 v = *(const float4*)((const float*)src + i);
            ushort4 o;
            o.x = f2b(v.x); o.y = f2b(v.y); o.z = f2b(v.z); o.w = f2b(v.w);
            *(ushort4*)(dst + i) = o;
        }
    }
}

// ---------------------------------------------------------------------------
// Tiled GEMM, bf16 in / bf16 out, fp32 accumulate.
// C[m][n] = sum_k A[m][k] * (TRANS_B ? B[n][k] : B[k][n])  (+bias, softsign)
// 64x64 tile, BK=16, 256 threads, 4x4 acc/thread. M,N mult of 64; K mult 16.
// If aflag != nullptr and *aflag==0, A is fp32 (requires sA==0).
// ---------------------------------------------------------------------------
template<bool TRANS_B, bool BIAS, bool SOFTSIGN>
__global__ __launch_bounds__(256) void gemm_bf16(
    const u16* __restrict__ A, const u16* __restrict__ B,
    const u16* __restrict__ bias, u16* __restrict__ C,
    const int* __restrict__ aflag,
    int M, int Nn, int K, int lda, int ldb, int ldc,
    long sA, long sB, long sC)
{
    const int bz = blockIdx.z;
    A += (long)bz * sA;
    B += (long)bz * sB;
    C += (long)bz * sC;
    const bool af32 = (aflag != nullptr) && (*aflag == 0);

    const int n0 = blockIdx.x * 64;
    const int m0 = blockIdx.y * 64;
    const int tid = threadIdx.x;     // 0..255
    const int tx = tid & 15;
    const int ty = tid >> 4;

    __shared__ float As[16][64];   // As[k][m]
    __shared__ float Bs[16][64];   // Bs[k][n]

    float acc[4][4] = {};

    const int rowL = tid >> 2;        // 0..63
    const int kqL  = (tid & 3) << 2;  // 0,4,8,12

    for (int k0 = 0; k0 < K; k0 += 16) {
        {
            const long aoff = (long)(m0 + rowL) * lda + k0 + kqL;
            if (af32) {
                const float4 av = *(const float4*)((const float*)A + aoff);
                As[kqL + 0][rowL] = av.x;
                As[kqL + 1][rowL] = av.y;
                As[kqL + 2][rowL] = av.z;
                As[kqL + 3][rowL] = av.w;
            } else {
                const ushort4 av = *(const ushort4*)(A + aoff);
                As[kqL + 0][rowL] = b2f(av.x);
                As[kqL + 1][rowL] = b2f(av.y);
                As[kqL + 2][rowL] = b2f(av.z);
                As[kqL + 3][rowL] = b2f(av.w);
            }
        }
        if (TRANS_B) {
            const ushort4 bv = *(const ushort4*)(B + (long)(n0 + rowL) * ldb + k0 + kqL);
            Bs[kqL + 0][rowL] = b2f(bv.x);
            Bs[kqL + 1][rowL] = b2f(bv.y);
            Bs[kqL + 2][rowL] = b2f(bv.z);
            Bs[kqL + 3][rowL] = b2f(bv.w);
        } else {
            const int kr = tid >> 4;          // 0..15
            const int nc = (tid & 15) << 2;   // 0..60
            const ushort4 bv = *(const ushort4*)(B + (long)(k0 + kr) * ldb + n0 + nc);
            float4 t;
            t.x = b2f(bv.x); t.y = b2f(bv.y); t.z = b2f(bv.z); t.w = b2f(bv.w);
            *(float4*)&Bs[kr][nc] = t;
        }
        __syncthreads();

        #pragma unroll
        for (int k = 0; k < 16; ++k) {
            const float4 a = *(const float4*)&As[k][ty << 2];
            const float4 b = *(const float4*)&Bs[k][tx << 2];
            const float ar[4] = {a.x, a.y, a.z, a.w};
            const float br[4] = {b.x, b.y, b.z, b.w};
            #pragma unroll
            for (int i = 0; i < 4; ++i)
                #pragma unroll
                for (int j = 0; j < 4; ++j)
                    acc[i][j] = fmaf(ar[i], br[j], acc[i][j]);
        }
        __syncthreads();
    }

    #pragma unroll
    for (int i = 0; i < 4; ++i) {
        const int m = m0 + (ty << 2) + i;
        ushort4 o;
        u16* op = &o.x;
        #pragma unroll
        for (int j = 0; j < 4; ++j) {
            float v = acc[i][j];
            if (BIAS) v += b2f(bias[n0 + (tx << 2) + j]);
            if (SOFTSIGN) v = v / (1.0f + fabsf(v));
            op[j] = f2b(v);
        }
        *(ushort4*)(C + (long)m * ldc + n0 + (tx << 2)) = o;
    }
}

// ---------------------------------------------------------------------------
// BN stats over (N, L) per channel f (layout (N, FC, Lc)). One block/channel.
// Writes folded scale/shift (fp32): y = x*ss[f] + ss[FC+f]. gamma/beta bf16.
// ---------------------------------------------------------------------------
__global__ __launch_bounds__(256) void bn_stats(
    const u16* __restrict__ src, const u16* __restrict__ gamma,
    const u16* __restrict__ beta, float* __restrict__ ss,
    int Lc, int nOuter)
{
    const int f = blockIdx.x;
    const long outerStride = (long)FC * Lc;
    const u16* base = src + (long)f * Lc;

    float s1 = 0.f, s2 = 0.f;
    for (int n = 0; n < nOuter; ++n) {
        const u16* p = base + n * outerStride;
        for (int i = (threadIdx.x << 2); i < Lc; i += (blockDim.x << 2)) {
            const ushort4 v = *(const ushort4*)(p + i);
            const float a = b2f(v.x), b = b2f(v.y), c = b2f(v.z), d = b2f(v.w);
            s1 += a + b + c + d;
            s2 += a * a + b * b + c * c + d * d;
        }
    }

    __shared__ float r1[256], r2[256];
    const int tid = threadIdx.x;
    r1[tid] = s1;
    r2[tid] = s2;
    __syncthreads();
    for (int s = 128; s > 0; s >>= 1) {
        if (tid < s) { r1[tid] += r1[tid + s]; r2[tid] += r2[tid + s]; }
        __syncthreads();
    }
    if (tid == 0) {
        const float cnt  = (float)nOuter * (float)Lc;
        const float mean = r1[0] / cnt;
        const float var  = r2[0] / cnt - mean * mean;
        const float rstd = rsqrtf(var + BN_EPS);
        const float sc   = b2f(gamma[f]) * rstd;
        ss[f]      = sc;
        ss[FC + f] = b2f(beta[f]) - mean * sc;
    }
}

// ---------------------------------------------------------------------------
// dst = src*scale+shift (+ add). src bf16; add dtype per addflag; dst dtype
// per outflag (nullptr or *==1 -> bf16; *==0 -> fp32).
// ---------------------------------------------------------------------------
template<bool ADD>
__global__ __launch_bounds__(256) void bn_apply(
    const u16* __restrict__ src, const void* __restrict__ add,
    const int* __restrict__ addflag,
    const float* __restrict__ ss, void* __restrict__ dst,
    const int* __restrict__ outflag, long total4, int Lc)
{
    const bool addf32 = ADD && (addflag != nullptr) && (*addflag == 0);
    const bool outf32 = (outflag != nullptr) && (*outflag == 0);
    long i4 = (long)blockIdx.x * blockDim.x + threadIdx.x;
    const long stride = (long)gridDim.x * blockDim.x;
    for (; i4 < total4; i4 += stride) {
        const long i = i4 << 2;
        const int c = (int)((i / Lc) % FC);
        const float sc = ss[c];
        const float sh = ss[FC + c];
        const ushort4 v = *(const ushort4*)(src + i);
        float o0 = fmaf(b2f(v.x), sc, sh);
        float o1 = fmaf(b2f(v.y), sc, sh);
        float o2 = fmaf(b2f(v.z), sc, sh);
        float o3 = fmaf(b2f(v.w), sc, sh);
        if (ADD) {
            if (addf32) {
                const float4 a = *(const float4*)((const float*)add + i);
                o0 += a.x; o1 += a.y; o2 += a.z; o3 += a.w;
            } else {
                const ushort4 a = *(const ushort4*)((const u16*)add + i);
                o0 += b2f(a.x); o1 += b2f(a.y); o2 += b2f(a.z); o3 += b2f(a.w);
            }
        }
        if (outf32) {
            float4 o; o.x = o0; o.y = o1; o.z = o2; o.w = o3;
            *(float4*)((float*)dst + i) = o;
        } else {
            ushort4 o;
            o.x = f2b(o0); o.y = f2b(o1); o.z = f2b(o2); o.w = f2b(o3);
            *(ushort4*)((u16*)dst + i) = o;
        }
    }
}

// dst = a + b + bias[channel], all bf16
__global__ __launch_bounds__(256) void add3_bias(
    const u16* __restrict__ a, const u16* __restrict__ b,
    const u16* __restrict__ bias, u16* __restrict__ dst,
    long total4, int Lc)
{
    long i4 = (long)blockIdx.x * blockDim.x + threadIdx.x;
    const long stride = (long)gridDim.x * blockDim.x;
    for (; i4 < total4; i4 += stride) {
        const long i = i4 << 2;
        const int c = (int)((i / Lc) % FC);
        const float bs = b2f(bias[c]);
        const ushort4 va = *(const ushort4*)(a + i);
        const ushort4 vb = *(const ushort4*)(b + i);
        ushort4 o;
        o.x = f2b(b2f(va.x) + b2f(vb.x) + bs);
        o.y = f2b(b2f(va.y) + b2f(vb.y) + bs);
        o.z = f2b(b2f(va.z) + b2f(vb.z) + bs);
        o.w = f2b(b2f(va.w) + b2f(vb.w) + bs);
        *(ushort4*)(dst + i) = o;
    }
}

extern "C" void kernel_launch(void* const* d_in, const int* in_sizes, int n_in,
                              void* d_out, int out_size, void* d_ws, size_t ws_size,
                              hipStream_t stream)
{
    const size_t MiB = (size_t)1 << 20;
    const long sFH = (long)FC * HH;   // 1,048,576
    const long sFF = (long)FC * FC;   // 1,048,576
    const long sFD = (long)FC * DD;   //   524,288
    const long VE  = (long)NB * FC * HH;   // 33,554,432
    const long PE  = (long)NB * FC * DD;   // 16,777,216

    // ---- workspace layout (total ~= 68 MiB + cb*4 MiB + 16 KiB) ----
    u16* V  = (u16*)d_ws;                            // 64 MiB: v (N,F,H)
    u16* WC = (u16*)((char*)d_ws + 64 * MiB);        // packed bf16 params

    long off[16];
    long cur = 0;
    for (int i = 1; i < 15; ++i) { off[i] = cur; cur += ((long)in_sizes[i] + 7) & ~7L; }
    size_t scrOff = (((size_t)(64 * MiB) + (size_t)cur * 2) + 255) & ~(size_t)255;

    int cb = 4;
    while (cb > 1 && scrOff + (size_t)cb * 4 * MiB + 16384 > ws_size) cb--;

    u16*   SCR_W  = (u16*)((char*)d_ws + scrOff);    // cb*2 MiB: w chunk
    u16*   SCR_V2 = SCR_W + (long)cb * sFF;          // cb*2 MiB: v2 chunk
    float* SS     = (float*)(SCR_V2 + (long)cb * sFH);  // 8 KiB
    int*   FLAG   = (int*)(SS + 2 * FC);
    u16*   VX     = (u16*)d_out;   // 32 MiB: v3 -> s -> xr (overwritten by final out)
    u16*   V4     = V;             // reuse: v dead after correlation loop

    const dim3 blk(256);
    const dim3 egrid(4096);

    // 0. detect input dtype; convert all params to bf16
    detect_dtype<<<1, blk, 0, stream>>>((const u32*)d_in[0], FLAG);
    for (int i = 1; i < 15; ++i) {
        const long n4 = (long)in_sizes[i] / 4;
        const int g = (int)((n4 + 255) / 256) > 1024 ? 1024 : (int)((n4 + 255) / 256);
        convert_to_bf16<<<dim3(g > 0 ? g : 1), blk, 0, stream>>>(d_in[i], WC + off[i], n4, FLAG);
    }
    const u16* W0c = WC + off[1];
    const u16* b0c = WC + off[2];
    const u16* g0c = WC + off[3];
    const u16* be0c = WC + off[4];
    const u16* W1c = WC + off[5];
    const u16* b1c = WC + off[6];
    const u16* g1c = WC + off[7];
    const u16* be1c = WC + off[8];
    const u16* gfc = WC + off[9];
    const u16* bfc = WC + off[10];
    const u16* Wcc = WC + off[11];
    const u16* bcc = WC + off[12];
    const u16* goc = WC + off[13];
    const u16* boc = WC + off[14];
    const u16* x = (const u16*)d_in[0];  // dual dtype via FLAG

    // 1. v = x @ W0^T + b0    (M=32768, N=1024, K=512), NT
    gemm_bf16<true, true, false><<<dim3(HH / 64, (NB * FC) / 64, 1), blk, 0, stream>>>(
        x, W0c, b0c, V, FLAG, NB * FC, HH, DD, DD, DD, HH, 0, 0, 0);

    // 2-3. v = BN0(v)
    bn_stats<<<FC, blk, 0, stream>>>(V, g0c, be0c, SS, HH, NB);
    bn_apply<false><<<egrid, blk, 0, stream>>>(V, nullptr, nullptr, SS, V, nullptr, VE / 4, HH);

    // 4-6 fused per chunk: w = softsign(v v^T); v2 = w @ v; v3 = v2 @ W1^T + b1
    for (int bz0 = 0; bz0 < NB; bz0 += cb) {
        const int c = (NB - bz0 < cb) ? (NB - bz0) : cb;
        gemm_bf16<true, false, true><<<dim3(FC / 64, FC / 64, c), blk, 0, stream>>>(
            V + bz0 * sFH, V + bz0 * sFH, nullptr, SCR_W, nullptr,
            FC, FC, HH, HH, HH, FC, sFH, sFH, sFF);
        gemm_bf16<false, false, false><<<dim3(HH / 64, FC / 64, c), blk, 0, stream>>>(
            SCR_W, V + bz0 * sFH, nullptr, SCR_V2, nullptr,
            FC, HH, FC, FC, HH, HH, sFF, sFH, sFH);
        gemm_bf16<true, true, false><<<dim3(DD / 64, (c * FC) / 64, 1), blk, 0, stream>>>(
            SCR_V2, W1c, b1c, VX + bz0 * sFD, nullptr,
            c * FC, DD, HH, HH, HH, DD, 0, 0, 0);
    }

    // 7-8. s = BN1(v3) + x   (in place in VX; x dual-dtype)
    bn_stats<<<FC, blk, 0, stream>>>(VX, g1c, be1c, SS, DD, NB);
    bn_apply<true><<<egrid, blk, 0, stream>>>(VX, x, FLAG, SS, VX, nullptr, PE / 4, DD);

    // 9-10. xr = BNf(s)      (in place in VX)
    bn_stats<<<FC, blk, 0, stream>>>(VX, gfc, bfc, SS, DD, NB);
    bn_apply<false><<<egrid, blk, 0, stream>>>(VX, nullptr, nullptr, SS, VX, nullptr, PE / 4, DD);

    // 11. v4 = Wc @ xr   per batch (M=F, N=D, K=F), NN -> V4 (reuses V)
    gemm_bf16<false, false, false><<<dim3(DD / 64, FC / 64, NB), blk, 0, stream>>>(
        Wcc, VX, nullptr, V4, nullptr, FC, DD, FC, FC, DD, DD, 0, sFD, sFD);

    // 12. t = v4 + bc + xr  (in place V4)
    add3_bias<<<egrid, blk, 0, stream>>>(V4, VX, bcc, V4, PE / 4, DD);

    // 13-14. out = BNo(t); output dtype per FLAG
    bn_stats<<<FC, blk, 0, stream>>>(V4, goc, boc, SS, DD, NB);
    bn_apply<false><<<egrid, blk, 0, stream>>>(V4, nullptr, nullptr, SS, d_out, FLAG, PE / 4, DD);
}

// Round 5
// 874.044 us; speedup vs baseline: 4.1542x; 4.1542x over previous
//
#include <hip/hip_runtime.h>
#include <stdint.h>

#define NB 32
#define FC 1024
#define DD 512
#define HH 1024
#define BN_EPS 1e-5f

typedef unsigned short u16;
typedef unsigned int u32;
typedef __attribute__((ext_vector_type(8))) short bf16x8;   // 8 bf16 = 4 VGPRs
typedef __attribute__((ext_vector_type(4))) float f32x4;

#define AS1 __attribute__((address_space(1)))
#define AS3 __attribute__((address_space(3)))

__device__ __forceinline__ float b2f(u16 u) {
    union { u32 i; float f; } v;
    v.i = ((u32)u) << 16;
    return v.f;
}
__device__ __forceinline__ u16 f2b(float f) {
    union { float f; u32 i; } v;
    v.f = f;
    const u32 b = v.i;
    return (u16)((b + 0x7FFFu + ((b >> 16) & 1u)) >> 16);
}

// async global->LDS, 16B per lane; lds dest must be wave-uniform base
__device__ __forceinline__ void gld16(const u16* g, u16* l) {
    __builtin_amdgcn_global_load_lds((const AS1 u32*)g, (AS3 u32*)l, 16, 0, 0);
}

// ---------------------------------------------------------------------------
// Dtype detection: flag=1 if x is bf16 pairs, 0 if fp32 (R4-verified: fp32).
// ---------------------------------------------------------------------------
__global__ __launch_bounds__(256) void detect_dtype(
    const u32* __restrict__ x, int* __restrict__ flag)
{
    __shared__ int cnt[256];
    int c = 0;
    for (int i = threadIdx.x; i < 4096; i += 256) {
        const u32 lo = x[i] & 0xFFFFu;
        const u32 e = (lo >> 7) & 0xFFu;
        if (e >= 0x68u && e <= 0x85u) c++;
    }
    cnt[threadIdx.x] = c;
    __syncthreads();
    for (int s = 128; s > 0; s >>= 1) {
        if (threadIdx.x < (unsigned)s) cnt[threadIdx.x] += cnt[threadIdx.x + s];
        __syncthreads();
    }
    if (threadIdx.x == 0) flag[0] = (cnt[0] > 2048) ? 1 : 0;
}

__global__ __launch_bounds__(256) void convert_to_bf16(
    const void* __restrict__ src, u16* __restrict__ dst, long n4,
    const int* __restrict__ flag)
{
    const bool isbf = (*flag != 0);
    long i4 = (long)blockIdx.x * blockDim.x + threadIdx.x;
    const long stride = (long)gridDim.x * blockDim.x;
    for (; i4 < n4; i4 += stride) {
        const long i = i4 << 2;
        if (isbf) {
            *(ushort4*)(dst + i) = *(const ushort4*)((const u16*)src + i);
        } else {
            const float4 v = *(const float4*)((const float*)src + i);
            ushort4 o;
            o.x = f2b(v.x); o.y = f2b(v.y); o.z = f2b(v.z); o.w = f2b(v.w);
            *(ushort4*)(dst + i) = o;
        }
    }
}

// ---------------------------------------------------------------------------
// MFMA GEMM (NT): C[m][n] = sum_k A[m][k]*B[n][k]  (+bias[n], softsign)
// 128x128 tile, BK=32, 256 thr = 4 waves, each wave 64x64 (4x4 of 16x16x32).
// M,N mult of 128; K mult of 32. bf16 in/out, fp32 accum.
// ---------------------------------------------------------------------------
template<bool BIAS, bool SOFTSIGN>
__global__ __launch_bounds__(256) void gemm_mfma_nt(
    const u16* __restrict__ A, const u16* __restrict__ B,
    const u16* __restrict__ bias, u16* __restrict__ C,
    int M, int N, int K, int lda, int ldb, int ldc,
    long sA, long sB, long sC)
{
    const int bz = blockIdx.z;
    A += (long)bz * sA;
    B += (long)bz * sB;
    C += (long)bz * sC;

    const int n0 = blockIdx.x * 128;
    const int m0 = blockIdx.y * 128;
    const int tid = threadIdx.x;
    const int lane = tid & 63;
    const int wv = tid >> 6;           // wave 0..3
    const int wr = (wv >> 1) * 64;     // wave row offset in tile
    const int wc = (wv & 1) * 64;      // wave col offset in tile
    const int lm = lane & 15;
    const int q  = lane >> 4;          // k-group 0..3

    __shared__ __align__(16) u16 As[128 * 32];  // [m][k] rows of 64B
    __shared__ __align__(16) u16 Bs[128 * 32];  // [n][k]

    f32x4 acc[4][4] = {};

    // staging: each wave fills 2 chunks of 16 rows (1KiB each) for A and B
    const int c0 = wv * 2, c1 = wv * 2 + 1;
    const int sr0 = c0 * 16 + (lane >> 2);
    const int sr1 = c1 * 16 + (lane >> 2);
    const int sk  = (lane & 3) * 8;    // k element offset (8 bf16 = 16B)
    const u16* gA0 = A + (long)(m0 + sr0) * lda + sk;
    const u16* gA1 = A + (long)(m0 + sr1) * lda + sk;
    const u16* gB0 = B + (long)(n0 + sr0) * ldb + sk;
    const u16* gB1 = B + (long)(n0 + sr1) * ldb + sk;
    u16* lA0 = &As[c0 * 512];
    u16* lA1 = &As[c1 * 512];
    u16* lB0 = &Bs[c0 * 512];
    u16* lB1 = &Bs[c1 * 512];

    for (int k0 = 0; k0 < K; k0 += 32) {
        gld16(gA0 + k0, lA0);
        gld16(gA1 + k0, lA1);
        gld16(gB0 + k0, lB0);
        gld16(gB1 + k0, lB1);
        __syncthreads();   // drain vmcnt + barrier: staging visible

        bf16x8 a[4], b[4];
        #pragma unroll
        for (int i = 0; i < 4; ++i)
            a[i] = *(const bf16x8*)&As[(wr + 16 * i + lm) * 32 + q * 8];
        #pragma unroll
        for (int j = 0; j < 4; ++j)
            b[j] = *(const bf16x8*)&Bs[(wc + 16 * j + lm) * 32 + q * 8];
        #pragma unroll
        for (int i = 0; i < 4; ++i)
            #pragma unroll
            for (int j = 0; j < 4; ++j)
                acc[i][j] = __builtin_amdgcn_mfma_f32_16x16x32_bf16(
                    a[i], b[j], acc[i][j], 0, 0, 0);

        __syncthreads();   // all LDS reads done before next stage overwrites
    }

    // epilogue: C/D layout col=lane&15, row=(lane>>4)*4+reg
    #pragma unroll
    for (int i = 0; i < 4; ++i) {
        const int row = m0 + wr + 16 * i + 4 * q;
        #pragma unroll
        for (int j = 0; j < 4; ++j) {
            const int col = n0 + wc + 16 * j + lm;
            const float bj = BIAS ? b2f(bias[col]) : 0.0f;
            #pragma unroll
            for (int r = 0; r < 4; ++r) {
                float v = acc[i][j][r] + bj;
                if (SOFTSIGN) v = v / (1.0f + fabsf(v));
                C[(long)(row + r) * ldc + col] = f2b(v);
            }
        }
    }
}

// ---------------------------------------------------------------------------
// bf16 tiled transpose: src [R][Cc] -> dst [Cc][R] per batch
// ---------------------------------------------------------------------------
__global__ __launch_bounds__(256) void transpose_bf16(
    const u16* __restrict__ src, u16* __restrict__ dst,
    int R, int Cc, long sS, long sD)
{
    __shared__ u16 t[32][33];
    const int bz = blockIdx.z;
    src += (long)bz * sS;
    dst += (long)bz * sD;
    const int c0 = blockIdx.x * 32;
    const int r0 = blockIdx.y * 32;
    const int lx = threadIdx.x & 31;
    const int ly = threadIdx.x >> 5;   // 0..7
    #pragma unroll
    for (int d = 0; d < 32; d += 8)
        t[ly + d][lx] = src[(long)(r0 + ly + d) * Cc + c0 + lx];
    __syncthreads();
    #pragma unroll
    for (int d = 0; d < 32; d += 8)
        dst[(long)(c0 + ly + d) * R + r0 + lx] = t[lx][ly + d];
}

// ---------------------------------------------------------------------------
// BN stats over (N, L) per channel f (layout (N, FC, Lc)). One block/channel.
// ---------------------------------------------------------------------------
__global__ __launch_bounds__(256) void bn_stats(
    const u16* __restrict__ src, const u16* __restrict__ gamma,
    const u16* __restrict__ beta, float* __restrict__ ss,
    int Lc, int nOuter)
{
    const int f = blockIdx.x;
    const long outerStride = (long)FC * Lc;
    const u16* base = src + (long)f * Lc;

    float s1 = 0.f, s2 = 0.f;
    for (int n = 0; n < nOuter; ++n) {
        const u16* p = base + n * outerStride;
        for (int i = (threadIdx.x << 2); i < Lc; i += (blockDim.x << 2)) {
            const ushort4 v = *(const ushort4*)(p + i);
            const float a = b2f(v.x), b = b2f(v.y), c = b2f(v.z), d = b2f(v.w);
            s1 += a + b + c + d;
            s2 += a * a + b * b + c * c + d * d;
        }
    }

    __shared__ float r1[256], r2[256];
    const int tid = threadIdx.x;
    r1[tid] = s1;
    r2[tid] = s2;
    __syncthreads();
    for (int s = 128; s > 0; s >>= 1) {
        if (tid < s) { r1[tid] += r1[tid + s]; r2[tid] += r2[tid + s]; }
        __syncthreads();
    }
    if (tid == 0) {
        const float cnt  = (float)nOuter * (float)Lc;
        const float mean = r1[0] / cnt;
        const float var  = r2[0] / cnt - mean * mean;
        const float rstd = rsqrtf(var + BN_EPS);
        const float sc   = b2f(gamma[f]) * rstd;
        ss[f]      = sc;
        ss[FC + f] = b2f(beta[f]) - mean * sc;
    }
}

// dst = src*scale+shift (+ add); add dtype per addflag, dst dtype per outflag
template<bool ADD>
__global__ __launch_bounds__(256) void bn_apply(
    const u16* __restrict__ src, const void* __restrict__ add,
    const int* __restrict__ addflag,
    const float* __restrict__ ss, void* __restrict__ dst,
    const int* __restrict__ outflag, long total4, int Lc)
{
    const bool addf32 = ADD && (addflag != nullptr) && (*addflag == 0);
    const bool outf32 = (outflag != nullptr) && (*outflag == 0);
    long i4 = (long)blockIdx.x * blockDim.x + threadIdx.x;
    const long stride = (long)gridDim.x * blockDim.x;
    for (; i4 < total4; i4 += stride) {
        const long i = i4 << 2;
        const int c = (int)((i / Lc) % FC);
        const float sc = ss[c];
        const float sh = ss[FC + c];
        const ushort4 v = *(const ushort4*)(src + i);
        float o0 = fmaf(b2f(v.x), sc, sh);
        float o1 = fmaf(b2f(v.y), sc, sh);
        float o2 = fmaf(b2f(v.z), sc, sh);
        float o3 = fmaf(b2f(v.w), sc, sh);
        if (ADD) {
            if (addf32) {
                const float4 a = *(const float4*)((const float*)add + i);
                o0 += a.x; o1 += a.y; o2 += a.z; o3 += a.w;
            } else {
                const ushort4 a = *(const ushort4*)((const u16*)add + i);
                o0 += b2f(a.x); o1 += b2f(a.y); o2 += b2f(a.z); o3 += b2f(a.w);
            }
        }
        if (outf32) {
            float4 o; o.x = o0; o.y = o1; o.z = o2; o.w = o3;
            *(float4*)((float*)dst + i) = o;
        } else {
            ushort4 o;
            o.x = f2b(o0); o.y = f2b(o1); o.z = f2b(o2); o.w = f2b(o3);
            *(ushort4*)((u16*)dst + i) = o;
        }
    }
}

// dst = a + b + bias[channel], all bf16
__global__ __launch_bounds__(256) void add3_bias(
    const u16* __restrict__ a, const u16* __restrict__ b,
    const u16* __restrict__ bias, u16* __restrict__ dst,
    long total4, int Lc)
{
    long i4 = (long)blockIdx.x * blockDim.x + threadIdx.x;
    const long stride = (long)gridDim.x * blockDim.x;
    for (; i4 < total4; i4 += stride) {
        const long i = i4 << 2;
        const int c = (int)((i / Lc) % FC);
        const float bs = b2f(bias[c]);
        const ushort4 va = *(const ushort4*)(a + i);
        const ushort4 vb = *(const ushort4*)(b + i);
        ushort4 o;
        o.x = f2b(b2f(va.x) + b2f(vb.x) + bs);
        o.y = f2b(b2f(va.y) + b2f(vb.y) + bs);
        o.z = f2b(b2f(va.z) + b2f(vb.z) + bs);
        o.w = f2b(b2f(va.w) + b2f(vb.w) + bs);
        *(ushort4*)(dst + i) = o;
    }
}

extern "C" void kernel_launch(void* const* d_in, const int* in_sizes, int n_in,
                              void* d_out, int out_size, void* d_ws, size_t ws_size,
                              hipStream_t stream)
{
    const size_t MiB = (size_t)1 << 20;
    const long sFH = (long)FC * HH;        // 1,048,576 elems (2 MiB bf16)
    const long sFF = (long)FC * FC;        // 1,048,576
    const long sFD = (long)FC * DD;        //   524,288 (1 MiB)
    const long VE  = (long)NB * FC * HH;   // 33,554,432 (64 MiB)
    const long PE  = (long)NB * FC * DD;   // 16,777,216 (32 MiB)

    // bf16 param packing offsets
    long off[16];
    long cur = 0;
    for (int i = 1; i < 15; ++i) { off[i] = cur; cur += ((long)in_sizes[i] + 7) & ~7L; }
    const size_t paramBytes = (size_t)cur * 2;

    // adaptive correlation chunk: scratch = cb*6 MiB (VT + W + V2)
    int cb = 8;
    while (cb > 1 &&
           64 * MiB + (size_t)cb * 6 * MiB + paramBytes + 16384 > ws_size)
        cb >>= 1;

    // ---- workspace layout ----
    u16* V   = (u16*)d_ws;                          // 64 MiB: v (N,F,H)
    u16* VT  = (u16*)((char*)d_ws + 64 * MiB);      // cb*2 MiB: v^T chunk
    u16* WW  = VT + (long)cb * sFH;                 // cb*2 MiB: w chunk
    u16* V2  = WW + (long)cb * sFF;                 // cb*2 MiB: v2 chunk
    u16* WC  = V2 + (long)cb * sFH;                 // packed bf16 params
    char* tail = (char*)(WC + cur);
    tail = (char*)(((uintptr_t)tail + 255) & ~(uintptr_t)255);
    float* SS   = (float*)tail;                     // 8 KiB folded BN
    int*   FLAG = (int*)(SS + 2 * FC);
    // d_out (fp32 out => 64 MiB): lower 32 MiB = VX (v3->s->xr), upper = XB
    u16* VX  = (u16*)d_out;
    u16* XB  = (u16*)d_out + PE;                    // x as bf16 (dead before VX live)
    u16* V4  = V;                                   // v4/t (N,F,D) reuses V
    u16* XRT = V + PE;                              // xr^T reuses V upper half

    const dim3 blk(256);
    const dim3 egrid(4096);

    // 0. detect dtype; convert params + x to bf16
    detect_dtype<<<1, blk, 0, stream>>>((const u32*)d_in[0], FLAG);
    for (int i = 1; i < 15; ++i) {
        const long n4 = (long)in_sizes[i] / 4;
        int g = (int)((n4 + 255) / 256);
        if (g > 1024) g = 1024;
        if (g < 1) g = 1;
        convert_to_bf16<<<dim3(g), blk, 0, stream>>>(d_in[i], WC + off[i], n4, FLAG);
    }
    convert_to_bf16<<<dim3(1024), blk, 0, stream>>>(d_in[0], XB, PE / 4, FLAG);

    const u16* W0c = WC + off[1];
    const u16* b0c = WC + off[2];
    const u16* g0c = WC + off[3];
    const u16* be0c = WC + off[4];
    const u16* W1c = WC + off[5];
    const u16* b1c = WC + off[6];
    const u16* g1c = WC + off[7];
    const u16* be1c = WC + off[8];
    const u16* gfc = WC + off[9];
    const u16* bfc = WC + off[10];
    const u16* Wcc = WC + off[11];
    const u16* bcc = WC + off[12];
    const u16* goc = WC + off[13];
    const u16* boc = WC + off[14];

    // 1. v = x @ W0^T + b0   (M=32768, N=1024, K=512)
    gemm_mfma_nt<true, false><<<dim3(HH / 128, (NB * FC) / 128, 1), blk, 0, stream>>>(
        XB, W0c, b0c, V, NB * FC, HH, DD, DD, DD, HH, 0, 0, 0);

    // 2-3. v = BN0(v)
    bn_stats<<<FC, blk, 0, stream>>>(V, g0c, be0c, SS, HH, NB);
    bn_apply<false><<<egrid, blk, 0, stream>>>(V, nullptr, nullptr, SS, V, nullptr, VE / 4, HH);

    // 4-6 per chunk: vT; w = softsign(v v^T); v2 = w @ v (via vT); v3 = v2 @ W1^T + b1
    for (int bz0 = 0; bz0 < NB; bz0 += cb) {
        const int c = (NB - bz0 < cb) ? (NB - bz0) : cb;
        transpose_bf16<<<dim3(HH / 32, FC / 32, c), blk, 0, stream>>>(
            V + bz0 * sFH, VT, FC, HH, sFH, sFH);
        gemm_mfma_nt<false, true><<<dim3(FC / 128, FC / 128, c), blk, 0, stream>>>(
            V + bz0 * sFH, V + bz0 * sFH, nullptr, WW,
            FC, FC, HH, HH, HH, FC, sFH, sFH, sFF);
        gemm_mfma_nt<false, false><<<dim3(HH / 128, FC / 128, c), blk, 0, stream>>>(
            WW, VT, nullptr, V2,
            FC, HH, FC, FC, FC, HH, sFF, sFH, sFH);
        gemm_mfma_nt<true, false><<<dim3(DD / 128, (c * FC) / 128, 1), blk, 0, stream>>>(
            V2, W1c, b1c, VX + bz0 * sFD,
            c * FC, DD, HH, HH, HH, DD, 0, 0, 0);
    }

    // 7-8. s = BN1(v3) + x   (in place in VX; x fp32/bf16 per FLAG)
    bn_stats<<<FC, blk, 0, stream>>>(VX, g1c, be1c, SS, DD, NB);
    bn_apply<true><<<egrid, blk, 0, stream>>>(VX, d_in[0], FLAG, SS, VX, nullptr, PE / 4, DD);

    // 9-10. xr = BNf(s)      (in place in VX)
    bn_stats<<<FC, blk, 0, stream>>>(VX, gfc, bfc, SS, DD, NB);
    bn_apply<false><<<egrid, blk, 0, stream>>>(VX, nullptr, nullptr, SS, VX, nullptr, PE / 4, DD);

    // 11. xr^T, then v4 = Wc @ xr  (NT via xr^T) -> V4
    transpose_bf16<<<dim3(DD / 32, FC / 32, NB), blk, 0, stream>>>(
        VX, XRT, FC, DD, sFD, sFD);
    gemm_mfma_nt<false, false><<<dim3(DD / 128, FC / 128, NB), blk, 0, stream>>>(
        Wcc, XRT, nullptr, V4, FC, DD, FC, FC, FC, DD, 0, sFD, sFD);

    // 12. t = v4 + bc + xr  (in place V4)
    add3_bias<<<egrid, blk, 0, stream>>>(V4, VX, bcc, V4, PE / 4, DD);

    // 13-14. out = BNo(t); out dtype per FLAG
    bn_stats<<<FC, blk, 0, stream>>>(V4, goc, boc, SS, DD, NB);
    bn_apply<false><<<egrid, blk, 0, stream>>>(V4, nullptr, nullptr, SS, d_out, FLAG, PE / 4, DD);
}

// Round 6
// 780.426 us; speedup vs baseline: 4.6525x; 1.1200x over previous
//
#include <hip/hip_runtime.h>
#include <stdint.h>

#define NB 32
#define FC 1024
#define DD 512
#define HH 1024
#define BN_EPS 1e-5f

typedef unsigned short u16;
typedef unsigned int u32;
typedef __attribute__((ext_vector_type(8))) short bf16x8;   // 8 bf16 = 4 VGPRs
typedef __attribute__((ext_vector_type(4))) float f32x4;
typedef __attribute__((ext_vector_type(8))) unsigned short ushort8v;

#define AS1 __attribute__((address_space(1)))
#define AS3 __attribute__((address_space(3)))

__device__ __forceinline__ float b2f(u16 u) {
    union { u32 i; float f; } v;
    v.i = ((u32)u) << 16;
    return v.f;
}
__device__ __forceinline__ u16 f2b(float f) {
    union { float f; u32 i; } v;
    v.f = f;
    const u32 b = v.i;
    return (u16)((b + 0x7FFFu + ((b >> 16) & 1u)) >> 16);
}

// async global->LDS, 16B per lane; lds dest must be wave-uniform base
__device__ __forceinline__ void gld16(const u16* g, u16* l) {
    __builtin_amdgcn_global_load_lds((const AS1 u32*)g, (AS3 u32*)l, 16, 0, 0);
}

// XCD-aware tile swizzle: lin%8 = XCD slab over (m,z); each XCD iterates n
// fastest within its slab -> A-tile reuse lands in one XCD's L2.
// Requires gridDim.y*gridDim.z % 8 == 0 (all our grids satisfy this).
__device__ __forceinline__ void swizzle_tiles(int& mt, int& nt, int& zt) {
    const int gx = gridDim.x, gy = gridDim.y, gz = gridDim.z;
    const int mzTot = gy * gz;
    if ((mzTot & 7) != 0) { nt = blockIdx.x; mt = blockIdx.y; zt = blockIdx.z; return; }
    long lin = ((long)blockIdx.z * gy + blockIdx.y) * gx + blockIdx.x;
    const int slab = mzTot >> 3;
    const int xcd = (int)(lin & 7);
    const long idx = lin >> 3;
    nt = (int)(idx % gx);
    const int mz = (int)(idx / gx) + xcd * slab;
    mt = mz % gy;
    zt = mz / gy;
}

// ---------------------------------------------------------------------------
// Dtype detection: flag=1 if x is bf16 pairs, 0 if fp32 (R4-verified: fp32).
// ---------------------------------------------------------------------------
__global__ __launch_bounds__(256) void detect_dtype(
    const u32* __restrict__ x, int* __restrict__ flag)
{
    __shared__ int cnt[256];
    int c = 0;
    for (int i = threadIdx.x; i < 4096; i += 256) {
        const u32 lo = x[i] & 0xFFFFu;
        const u32 e = (lo >> 7) & 0xFFu;
        if (e >= 0x68u && e <= 0x85u) c++;
    }
    cnt[threadIdx.x] = c;
    __syncthreads();
    for (int s = 128; s > 0; s >>= 1) {
        if (threadIdx.x < (unsigned)s) cnt[threadIdx.x] += cnt[threadIdx.x + s];
        __syncthreads();
    }
    if (threadIdx.x == 0) flag[0] = (cnt[0] > 2048) ? 1 : 0;
}

__global__ __launch_bounds__(256) void convert_to_bf16(
    const void* __restrict__ src, u16* __restrict__ dst, long n4,
    const int* __restrict__ flag)
{
    const bool isbf = (*flag != 0);
    long i4 = (long)blockIdx.x * blockDim.x + threadIdx.x;
    const long stride = (long)gridDim.x * blockDim.x;
    for (; i4 < n4; i4 += stride) {
        const long i = i4 << 2;
        if (isbf) {
            *(ushort4*)(dst + i) = *(const ushort4*)((const u16*)src + i);
        } else {
            const float4 v = *(const float4*)((const float*)src + i);
            ushort4 o;
            o.x = f2b(v.x); o.y = f2b(v.y); o.z = f2b(v.z); o.w = f2b(v.w);
            *(ushort4*)(dst + i) = o;
        }
    }
}

// ---------------------------------------------------------------------------
// MFMA GEMM (NT): C[m][n] = sum_k A[m][k]*B[n][k]  (+bias[n], softsign)
// 128x128 tile, BK=32, 256 thr = 4 waves, each wave 64x64 (4x4 of 16x16x32).
// M,N mult of 128; K mult of 32. bf16 in/out, fp32 accum.
// Epilogue repacks through per-wave LDS for coalesced 16B stores.
// ---------------------------------------------------------------------------
template<bool BIAS, bool SOFTSIGN>
__global__ __launch_bounds__(256) void gemm_mfma_nt(
    const u16* __restrict__ A, const u16* __restrict__ B,
    const u16* __restrict__ bias, u16* __restrict__ C,
    int M, int N, int K, int lda, int ldb, int ldc,
    long sA, long sB, long sC)
{
    int mt, nt, zt;
    swizzle_tiles(mt, nt, zt);
    A += (long)zt * sA;
    B += (long)zt * sB;
    C += (long)zt * sC;

    const int n0 = nt * 128;
    const int m0 = mt * 128;
    const int tid = threadIdx.x;
    const int lane = tid & 63;
    const int wv = tid >> 6;           // wave 0..3
    const int wr = (wv >> 1) * 64;     // wave row offset in tile
    const int wc = (wv & 1) * 64;      // wave col offset in tile
    const int lm = lane & 15;
    const int q  = lane >> 4;          // k-group 0..3

    // staging 16 KiB (As 8K + Bs 8K); epilogue overlays 4 waves x 16x65 fp32
    __shared__ __align__(16) u16 smem[8320 * 2];
    u16* As = smem;                    // [128][32]
    u16* Bs = smem + 128 * 32;         // [128][32]

    f32x4 acc[4][4] = {};

    // staging: each wave fills 2 chunks of 16 rows (1KiB each) for A and B
    const int c0 = wv * 2, c1 = wv * 2 + 1;
    const int sr0 = c0 * 16 + (lane >> 2);
    const int sr1 = c1 * 16 + (lane >> 2);
    const int sk  = (lane & 3) * 8;    // k element offset (8 bf16 = 16B)
    const u16* gA0 = A + (long)(m0 + sr0) * lda + sk;
    const u16* gA1 = A + (long)(m0 + sr1) * lda + sk;
    const u16* gB0 = B + (long)(n0 + sr0) * ldb + sk;
    const u16* gB1 = B + (long)(n0 + sr1) * ldb + sk;
    u16* lA0 = &As[c0 * 512];
    u16* lA1 = &As[c1 * 512];
    u16* lB0 = &Bs[c0 * 512];
    u16* lB1 = &Bs[c1 * 512];

    for (int k0 = 0; k0 < K; k0 += 32) {
        gld16(gA0 + k0, lA0);
        gld16(gA1 + k0, lA1);
        gld16(gB0 + k0, lB0);
        gld16(gB1 + k0, lB1);
        __syncthreads();   // drain vmcnt + barrier: staging visible

        bf16x8 a[4], b[4];
        #pragma unroll
        for (int i = 0; i < 4; ++i)
            a[i] = *(const bf16x8*)&As[(wr + 16 * i + lm) * 32 + q * 8];
        #pragma unroll
        for (int j = 0; j < 4; ++j)
            b[j] = *(const bf16x8*)&Bs[(wc + 16 * j + lm) * 32 + q * 8];
        #pragma unroll
        for (int i = 0; i < 4; ++i)
            #pragma unroll
            for (int j = 0; j < 4; ++j)
                acc[i][j] = __builtin_amdgcn_mfma_f32_16x16x32_bf16(
                    a[i], b[j], acc[i][j], 0, 0, 0);

        __syncthreads();   // all LDS reads done before next stage overwrites
    }

    // epilogue: per-wave LDS repack (16 rows x 64 cols fp32, stride 65)
    // then coalesced 2x16B bf16 stores per lane per row-group.
    float* rep = (float*)smem + wv * (16 * 65);
    const int rr = lane >> 2;          // reader row 0..15
    const int cg = lane & 3;           // reader col group (16 cols)
    #pragma unroll
    for (int i = 0; i < 4; ++i) {
        #pragma unroll
        for (int j = 0; j < 4; ++j) {
            const int col = 16 * j + lm;
            const float bj = BIAS ? b2f(bias[n0 + wc + col]) : 0.0f;
            #pragma unroll
            for (int r = 0; r < 4; ++r) {
                float v = acc[i][j][r] + bj;
                if (SOFTSIGN) v = v / (1.0f + fabsf(v));
                rep[(q * 4 + r) * 65 + col] = v;
            }
        }
        // intra-wave LDS RAW: compiler orders via lgkmcnt (per-wave buffer)
        const float* lr = rep + rr * 65 + cg * 16;
        const float4 f0 = *(const float4*)(lr + 0);
        const float4 f1 = *(const float4*)(lr + 4);
        const float4 f2 = *(const float4*)(lr + 8);
        const float4 f3 = *(const float4*)(lr + 12);
        ushort8v o0, o1;
        o0[0] = f2b(f0.x); o0[1] = f2b(f0.y); o0[2] = f2b(f0.z); o0[3] = f2b(f0.w);
        o0[4] = f2b(f1.x); o0[5] = f2b(f1.y); o0[6] = f2b(f1.z); o0[7] = f2b(f1.w);
        o1[0] = f2b(f2.x); o1[1] = f2b(f2.y); o1[2] = f2b(f2.z); o1[3] = f2b(f2.w);
        o1[4] = f2b(f3.x); o1[5] = f2b(f3.y); o1[6] = f2b(f3.z); o1[7] = f2b(f3.w);
        u16* cp = C + (long)(m0 + wr + 16 * i + rr) * ldc + n0 + wc + cg * 16;
        *(ushort8v*)cp = o0;
        *(ushort8v*)(cp + 8) = o1;
    }
}

// ---------------------------------------------------------------------------
// bf16 tiled transpose: src [R][Cc] -> dst [Cc][R] per batch
// ---------------------------------------------------------------------------
__global__ __launch_bounds__(256) void transpose_bf16(
    const u16* __restrict__ src, u16* __restrict__ dst,
    int R, int Cc, long sS, long sD)
{
    __shared__ u16 t[32][33];
    const int bz = blockIdx.z;
    src += (long)bz * sS;
    dst += (long)bz * sD;
    const int c0 = blockIdx.x * 32;
    const int r0 = blockIdx.y * 32;
    const int lx = threadIdx.x & 31;
    const int ly = threadIdx.x >> 5;   // 0..7
    #pragma unroll
    for (int d = 0; d < 32; d += 8)
        t[ly + d][lx] = src[(long)(r0 + ly + d) * Cc + c0 + lx];
    __syncthreads();
    #pragma unroll
    for (int d = 0; d < 32; d += 8)
        dst[(long)(c0 + ly + d) * R + r0 + lx] = t[lx][ly + d];
}

// ---------------------------------------------------------------------------
// BN stats over (N, L) per channel f (layout (N, FC, Lc)). One block/channel.
// ---------------------------------------------------------------------------
__global__ __launch_bounds__(256) void bn_stats(
    const u16* __restrict__ src, const u16* __restrict__ gamma,
    const u16* __restrict__ beta, float* __restrict__ ss,
    int Lc, int nOuter)
{
    const int f = blockIdx.x;
    const long outerStride = (long)FC * Lc;
    const u16* base = src + (long)f * Lc;

    float s1 = 0.f, s2 = 0.f;
    for (int n = 0; n < nOuter; ++n) {
        const u16* p = base + n * outerStride;
        for (int i = (threadIdx.x << 2); i < Lc; i += (blockDim.x << 2)) {
            const ushort4 v = *(const ushort4*)(p + i);
            const float a = b2f(v.x), b = b2f(v.y), c = b2f(v.z), d = b2f(v.w);
            s1 += a + b + c + d;
            s2 += a * a + b * b + c * c + d * d;
        }
    }

    __shared__ float r1[256], r2[256];
    const int tid = threadIdx.x;
    r1[tid] = s1;
    r2[tid] = s2;
    __syncthreads();
    for (int s = 128; s > 0; s >>= 1) {
        if (tid < s) { r1[tid] += r1[tid + s]; r2[tid] += r2[tid + s]; }
        __syncthreads();
    }
    if (tid == 0) {
        const float cnt  = (float)nOuter * (float)Lc;
        const float mean = r1[0] / cnt;
        const float var  = r2[0] / cnt - mean * mean;
        const float rstd = rsqrtf(var + BN_EPS);
        const float sc   = b2f(gamma[f]) * rstd;
        ss[f]      = sc;
        ss[FC + f] = b2f(beta[f]) - mean * sc;
    }
}

// dst = src*scale+shift (+ add); add dtype per addflag, dst dtype per outflag
template<bool ADD>
__global__ __launch_bounds__(256) void bn_apply(
    const u16* __restrict__ src, const void* __restrict__ add,
    const int* __restrict__ addflag,
    const float* __restrict__ ss, void* __restrict__ dst,
    const int* __restrict__ outflag, long total4, int Lc)
{
    const bool addf32 = ADD && (addflag != nullptr) && (*addflag == 0);
    const bool outf32 = (outflag != nullptr) && (*outflag == 0);
    long i4 = (long)blockIdx.x * blockDim.x + threadIdx.x;
    const long stride = (long)gridDim.x * blockDim.x;
    for (; i4 < total4; i4 += stride) {
        const long i = i4 << 2;
        const int c = (int)((i / Lc) % FC);
        const float sc = ss[c];
        const float sh = ss[FC + c];
        const ushort4 v = *(const ushort4*)(src + i);
        float o0 = fmaf(b2f(v.x), sc, sh);
        float o1 = fmaf(b2f(v.y), sc, sh);
        float o2 = fmaf(b2f(v.z), sc, sh);
        float o3 = fmaf(b2f(v.w), sc, sh);
        if (ADD) {
            if (addf32) {
                const float4 a = *(const float4*)((const float*)add + i);
                o0 += a.x; o1 += a.y; o2 += a.z; o3 += a.w;
            } else {
                const ushort4 a = *(const ushort4*)((const u16*)add + i);
                o0 += b2f(a.x); o1 += b2f(a.y); o2 += b2f(a.z); o3 += b2f(a.w);
            }
        }
        if (outf32) {
            float4 o; o.x = o0; o.y = o1; o.z = o2; o.w = o3;
            *(float4*)((float*)dst + i) = o;
        } else {
            ushort4 o;
            o.x = f2b(o0); o.y = f2b(o1); o.z = f2b(o2); o.w = f2b(o3);
            *(ushort4*)((u16*)dst + i) = o;
        }
    }
}

// dst = a + b + bias[channel], all bf16
__global__ __launch_bounds__(256) void add3_bias(
    const u16* __restrict__ a, const u16* __restrict__ b,
    const u16* __restrict__ bias, u16* __restrict__ dst,
    long total4, int Lc)
{
    long i4 = (long)blockIdx.x * blockDim.x + threadIdx.x;
    const long stride = (long)gridDim.x * blockDim.x;
    for (; i4 < total4; i4 += stride) {
        const long i = i4 << 2;
        const int c = (int)((i / Lc) % FC);
        const float bs = b2f(bias[c]);
        const ushort4 va = *(const ushort4*)(a + i);
        const ushort4 vb = *(const ushort4*)(b + i);
        ushort4 o;
        o.x = f2b(b2f(va.x) + b2f(vb.x) + bs);
        o.y = f2b(b2f(va.y) + b2f(vb.y) + bs);
        o.z = f2b(b2f(va.z) + b2f(vb.z) + bs);
        o.w = f2b(b2f(va.w) + b2f(vb.w) + bs);
        *(ushort4*)(dst + i) = o;
    }
}

extern "C" void kernel_launch(void* const* d_in, const int* in_sizes, int n_in,
                              void* d_out, int out_size, void* d_ws, size_t ws_size,
                              hipStream_t stream)
{
    const size_t MiB = (size_t)1 << 20;
    const long sFH = (long)FC * HH;        // 1,048,576 elems (2 MiB bf16)
    const long sFF = (long)FC * FC;        // 1,048,576
    const long sFD = (long)FC * DD;        //   524,288 (1 MiB)
    const long VE  = (long)NB * FC * HH;   // 33,554,432 (64 MiB)
    const long PE  = (long)NB * FC * DD;   // 16,777,216 (32 MiB)

    // bf16 param packing offsets
    long off[16];
    long cur = 0;
    for (int i = 1; i < 15; ++i) { off[i] = cur; cur += ((long)in_sizes[i] + 7) & ~7L; }
    const size_t paramBytes = (size_t)cur * 2;

    // adaptive correlation chunk: scratch = cb*6 MiB (VT + W + V2)
    int cb = 16;
    while (cb > 1 &&
           64 * MiB + (size_t)cb * 6 * MiB + paramBytes + 16384 > ws_size)
        cb >>= 1;

    // ---- workspace layout ----
    u16* V   = (u16*)d_ws;                          // 64 MiB: v (N,F,H)
    u16* VT  = (u16*)((char*)d_ws + 64 * MiB);      // cb*2 MiB: v^T chunk
    u16* WW  = VT + (long)cb * sFH;                 // cb*2 MiB: w chunk
    u16* V2  = WW + (long)cb * sFF;                 // cb*2 MiB: v2 chunk
    u16* WC  = V2 + (long)cb * sFH;                 // packed bf16 params
    char* tail = (char*)(WC + cur);
    tail = (char*)(((uintptr_t)tail + 255) & ~(uintptr_t)255);
    float* SS   = (float*)tail;                     // 8 KiB folded BN
    int*   FLAG = (int*)(SS + 2 * FC);
    // d_out (fp32 out => 64 MiB): lower 32 MiB = VX (v3->s->xr), upper = XB
    u16* VX  = (u16*)d_out;
    u16* XB  = (u16*)d_out + PE;                    // x as bf16 (live until final store)
    u16* V4  = V;                                   // v4/t (N,F,D) reuses V
    u16* XRT = V + PE;                              // xr^T reuses V upper half

    const dim3 blk(256);
    const dim3 egrid(4096);

    // 0. detect dtype; convert params + x to bf16
    detect_dtype<<<1, blk, 0, stream>>>((const u32*)d_in[0], FLAG);
    for (int i = 1; i < 15; ++i) {
        const long n4 = (long)in_sizes[i] / 4;
        int g = (int)((n4 + 255) / 256);
        if (g > 1024) g = 1024;
        if (g < 1) g = 1;
        convert_to_bf16<<<dim3(g), blk, 0, stream>>>(d_in[i], WC + off[i], n4, FLAG);
    }
    convert_to_bf16<<<dim3(1024), blk, 0, stream>>>(d_in[0], XB, PE / 4, FLAG);

    const u16* W0c = WC + off[1];
    const u16* b0c = WC + off[2];
    const u16* g0c = WC + off[3];
    const u16* be0c = WC + off[4];
    const u16* W1c = WC + off[5];
    const u16* b1c = WC + off[6];
    const u16* g1c = WC + off[7];
    const u16* be1c = WC + off[8];
    const u16* gfc = WC + off[9];
    const u16* bfc = WC + off[10];
    const u16* Wcc = WC + off[11];
    const u16* bcc = WC + off[12];
    const u16* goc = WC + off[13];
    const u16* boc = WC + off[14];

    // 1. v = x @ W0^T + b0   (M=32768, N=1024, K=512)
    gemm_mfma_nt<true, false><<<dim3(HH / 128, (NB * FC) / 128, 1), blk, 0, stream>>>(
        XB, W0c, b0c, V, NB * FC, HH, DD, DD, DD, HH, 0, 0, 0);

    // 2-3. v = BN0(v)
    bn_stats<<<FC, blk, 0, stream>>>(V, g0c, be0c, SS, HH, NB);
    bn_apply<false><<<egrid, blk, 0, stream>>>(V, nullptr, nullptr, SS, V, nullptr, VE / 4, HH);

    // 4-6 per chunk: vT; w = softsign(v v^T); v2 = w @ v (via vT); v3 = v2 @ W1^T + b1
    for (int bz0 = 0; bz0 < NB; bz0 += cb) {
        const int c = (NB - bz0 < cb) ? (NB - bz0) : cb;
        transpose_bf16<<<dim3(HH / 32, FC / 32, c), blk, 0, stream>>>(
            V + bz0 * sFH, VT, FC, HH, sFH, sFH);
        gemm_mfma_nt<false, true><<<dim3(FC / 128, FC / 128, c), blk, 0, stream>>>(
            V + bz0 * sFH, V + bz0 * sFH, nullptr, WW,
            FC, FC, HH, HH, HH, FC, sFH, sFH, sFF);
        gemm_mfma_nt<false, false><<<dim3(HH / 128, FC / 128, c), blk, 0, stream>>>(
            WW, VT, nullptr, V2,
            FC, HH, FC, FC, FC, HH, sFF, sFH, sFH);
        gemm_mfma_nt<true, false><<<dim3(DD / 128, (c * FC) / 128, 1), blk, 0, stream>>>(
            V2, W1c, b1c, VX + bz0 * sFD,
            c * FC, DD, HH, HH, HH, DD, 0, 0, 0);
    }

    // 7-8. s = BN1(v3) + x   (in place in VX; x from bf16 copy XB)
    bn_stats<<<FC, blk, 0, stream>>>(VX, g1c, be1c, SS, DD, NB);
    bn_apply<true><<<egrid, blk, 0, stream>>>(VX, XB, nullptr, SS, VX, nullptr, PE / 4, DD);

    // 9-10. xr = BNf(s)      (in place in VX)
    bn_stats<<<FC, blk, 0, stream>>>(VX, gfc, bfc, SS, DD, NB);
    bn_apply<false><<<egrid, blk, 0, stream>>>(VX, nullptr, nullptr, SS, VX, nullptr, PE / 4, DD);

    // 11. xr^T, then v4 = Wc @ xr  (NT via xr^T) -> V4
    transpose_bf16<<<dim3(DD / 32, FC / 32, NB), blk, 0, stream>>>(
        VX, XRT, FC, DD, sFD, sFD);
    gemm_mfma_nt<false, false><<<dim3(DD / 128, FC / 128, NB), blk, 0, stream>>>(
        Wcc, XRT, nullptr, V4, FC, DD, FC, FC, FC, DD, 0, sFD, sFD);

    // 12. t = v4 + bc + xr  (in place V4)
    add3_bias<<<egrid, blk, 0, stream>>>(V4, VX, bcc, V4, PE / 4, DD);

    // 13-14. out = BNo(t); out dtype per FLAG
    bn_stats<<<FC, blk, 0, stream>>>(V4, goc, boc, SS, DD, NB);
    bn_apply<false><<<egrid, blk, 0, stream>>>(V4, nullptr, nullptr, SS, d_out, FLAG, PE / 4, DD);
}